// Round 1
// 1248.604 us; speedup vs baseline: 1.0592x; 1.0592x over previous
//
#include <hip/hip_runtime.h>
#include <stdint.h>

#define Bq 8
#define Hh 8
#define Ss 1024
#define Dd 64
#define Cc 21

typedef short bf16x8 __attribute__((ext_vector_type(8)));
typedef float f32x4 __attribute__((ext_vector_type(4)));

__device__ __forceinline__ unsigned short f2bf(float f) {
  union { float f; uint32_t u; } v; v.f = f;
  uint32_t u = v.u;
  u += 0x7FFFu + ((u >> 16) & 1u);  // round-to-nearest-even
  return (unsigned short)(u >> 16);
}

__device__ __forceinline__ bf16x8 pack8(float4 a, float4 b) {
  bf16x8 f;
  f[0] = (short)f2bf(a.x); f[1] = (short)f2bf(a.y);
  f[2] = (short)f2bf(a.z); f[3] = (short)f2bf(a.w);
  f[4] = (short)f2bf(b.x); f[5] = (short)f2bf(b.y);
  f[6] = (short)f2bf(b.z); f[7] = (short)f2bf(b.w);
  return f;
}

// ---------------------------------------------------------------------------
// K1: fused bias + QK^T + exp + partial row-sums.
// grid = b(8) x qtile(32) x kchunk(4); block = 512 thr = 8 waves; wave = head.
// Per 32-k subtile: all threads compute bias for ALL 8 heads into LDS (dtw
// read exactly once, shared across heads), each wave MFMAs its own head,
// streams p = exp(score+bias) to the attn region (pure stores, no RMW).
// Per-chunk row sums are written to out[row][kc] (out region doubles as
// scratch for the 4 partials; K2 reads then overwrites it).
// ---------------------------------------------------------------------------
__global__ __launch_bounds__(512) void score_kernel(
    const float* __restrict__ Q, const float* __restrict__ K,
    const float* __restrict__ dtw, const int* __restrict__ mask,
    const float* __restrict__ W, const float* __restrict__ bv,
    float* __restrict__ attn, float* __restrict__ lpart) {
  __shared__ float sBias[Hh][32][33];  // +1 pad: quad rows -> <=2-way conflict
  __shared__ float sWT[Cc][Hh];
  __shared__ float sb[Hh];

  const size_t SS = (size_t)Ss * Ss;
  int t = threadIdx.x;
  if (t < Hh * Cc) { int h = t / Cc; int c = t - h * Cc; sWT[c][h] = W[t]; }
  if (t < Hh) sb[t] = bv[t];

  int kc  = blockIdx.x & 3;
  int qt  = (blockIdx.x >> 2) & 31;
  int b   = blockIdx.x >> 7;
  int q0  = qt << 5;
  int kc0 = kc << 8;

  int w = t >> 6;       // wave = head
  int lane = t & 63;
  int quad = lane >> 4;
  int l16 = lane & 15;
  size_t bh = (size_t)b * Hh + w;

  // Q fragments, register-resident for the whole kernel (scaled by 1/8)
  bf16x8 qa[2][2];
  {
    const float* Qbase = Q + (bh * Ss + q0) * Dd;
#pragma unroll
    for (int mt = 0; mt < 2; ++mt)
#pragma unroll
      for (int ks = 0; ks < 2; ++ks) {
        const float* qp = Qbase + (mt * 16 + l16) * Dd + ks * 32 + quad * 8;
        float4 x = *(const float4*)qp;
        float4 y = *(const float4*)(qp + 4);
        x.x *= 0.125f; x.y *= 0.125f; x.z *= 0.125f; x.w *= 0.125f;
        y.x *= 0.125f; y.y *= 0.125f; y.z *= 0.125f; y.w *= 0.125f;
        qa[mt][ks] = pack8(x, y);
      }
  }

  const float* Kbase = K + (bh * Ss + kc0) * Dd;
  const float* dbase = dtw + (size_t)b * Cc * SS + (size_t)q0 * Ss + kc0;
  const int* mbase = mask + ((size_t)b * Ss + q0) * Ss + kc0;
  float* attp = attn + (bh * Ss + q0) * Ss + kc0;

  int qr = t >> 5;      // bias rows qr and qr+16
  int kcell = t & 31;   // bias col within 32-k subtile

  float lsum[2][4];
#pragma unroll
  for (int mt = 0; mt < 2; ++mt)
#pragma unroll
    for (int r = 0; r < 4; ++r) lsum[mt][r] = 0.f;

  for (int kt = 0; kt < 8; ++kt) {
    int k0 = kt << 5;
    // issue K loads early (global only; overlap with bias staging)
    float4 kf[8];
#pragma unroll
    for (int nt = 0; nt < 2; ++nt)
#pragma unroll
      for (int ks = 0; ks < 2; ++ks) {
        const float* kp =
            Kbase + (size_t)(k0 + nt * 16 + l16) * Dd + ks * 32 + quad * 8;
        kf[(nt * 2 + ks) * 2 + 0] = *(const float4*)kp;
        kf[(nt * 2 + ks) * 2 + 1] = *(const float4*)(kp + 4);
      }
    __syncthreads();  // prior-iter sBias consumed (iter0: sWT/sb staged)
    {
      // bias for 2 cells/thread x 8 heads; dtw read once, shared across heads
      const float* dp0 = dbase + (size_t)qr * Ss + k0 + kcell;
      const float* dp1 = dp0 + (size_t)16 * Ss;
      float a0[8], a1[8];
#pragma unroll
      for (int h = 0; h < 8; ++h) { a0[h] = sb[h]; a1[h] = sb[h]; }
#pragma unroll
      for (int c = 0; c < Cc; ++c) {
        float v0 = *dp0; dp0 += SS;
        float v1 = *dp1; dp1 += SS;
        float4 wa = *(const float4*)&sWT[c][0];
        float4 wb = *(const float4*)&sWT[c][4];
        a0[0] += wa.x * v0; a0[1] += wa.y * v0;
        a0[2] += wa.z * v0; a0[3] += wa.w * v0;
        a0[4] += wb.x * v0; a0[5] += wb.y * v0;
        a0[6] += wb.z * v0; a0[7] += wb.w * v0;
        a1[0] += wa.x * v1; a1[1] += wa.y * v1;
        a1[2] += wa.z * v1; a1[3] += wa.w * v1;
        a1[4] += wb.x * v1; a1[5] += wb.y * v1;
        a1[6] += wb.z * v1; a1[7] += wb.w * v1;
      }
      int m0 = mbase[(size_t)qr * Ss + k0 + kcell];
      int m1 = mbase[(size_t)(qr + 16) * Ss + k0 + kcell];
#pragma unroll
      for (int h = 0; h < 8; ++h) {
        sBias[h][qr][kcell] = m0 ? a0[h] : -1e9f;
        sBias[h][qr + 16][kcell] = m1 ? a1[h] : -1e9f;
      }
    }
    __syncthreads();
    bf16x8 kb[2][2];
#pragma unroll
    for (int nt = 0; nt < 2; ++nt)
#pragma unroll
      for (int ks = 0; ks < 2; ++ks)
        kb[nt][ks] = pack8(kf[(nt * 2 + ks) * 2], kf[(nt * 2 + ks) * 2 + 1]);
    f32x4 acc[2][2];
#pragma unroll
    for (int mt = 0; mt < 2; ++mt)
#pragma unroll
      for (int nt = 0; nt < 2; ++nt) {
        f32x4 a = {0.f, 0.f, 0.f, 0.f};
        a = __builtin_amdgcn_mfma_f32_16x16x32_bf16(qa[mt][0], kb[nt][0], a, 0, 0, 0);
        a = __builtin_amdgcn_mfma_f32_16x16x32_bf16(qa[mt][1], kb[nt][1], a, 0, 0, 0);
        acc[mt][nt] = a;
      }
#pragma unroll
    for (int mt = 0; mt < 2; ++mt)
#pragma unroll
      for (int nt = 0; nt < 2; ++nt)
#pragma unroll
        for (int r = 0; r < 4; ++r) {
          int lrow = mt * 16 + quad * 4 + r;
          float s = acc[mt][nt][r] + sBias[w][lrow][nt * 16 + l16];
          float p = __expf(s);  // masked cells: -1e9 -> exp underflows to 0
          lsum[mt][r] += p;
          attp[(size_t)lrow * Ss + k0 + nt * 16 + l16] = p;
        }
  }
  // reduce row sums over the 16 lanes sharing each row
#pragma unroll
  for (int off = 1; off < 16; off <<= 1)
#pragma unroll
    for (int mt = 0; mt < 2; ++mt)
#pragma unroll
      for (int r = 0; r < 4; ++r)
        lsum[mt][r] += __shfl_xor(lsum[mt][r], off, 64);
  if (l16 == 0) {
#pragma unroll
    for (int mt = 0; mt < 2; ++mt)
#pragma unroll
      for (int r = 0; r < 4; ++r)
        lpart[(bh * Ss + q0 + mt * 16 + quad * 4 + r) * Dd + kc] = lsum[mt][r];
  }
}

// ---------------------------------------------------------------------------
// K2: normalize + P@V. grid = (b,h)(64) x qtile(32); 256 thr = 4 waves.
// Reads the 4 partial row-sums stashed in the out region, scales p in place
// to the final attention, accumulates out = P@V via MFMA (k-parity split).
// ---------------------------------------------------------------------------
__global__ __launch_bounds__(256) void pv_kernel(
    const float* __restrict__ V, float* __restrict__ out,
    float* __restrict__ attn) {
  __shared__ unsigned short vt[Dd][72];  // V^T: [d][k], +8 pad
  __shared__ float linv[32];
  __shared__ float omerge[32][64];

  int t = threadIdx.x;
  int w = t >> 6;
  int lane = t & 63;
  int quad = lane >> 4;
  int l16 = lane & 15;

  int qt = blockIdx.x & 31;
  size_t bh = blockIdx.x >> 5;
  int q0 = qt << 5;

  const float* Vp = V + bh * Ss * Dd;
  float* attp = attn + (bh * Ss + q0) * Ss;
  float* outp = out + (bh * Ss + q0) * Dd;

  if (t < 32) {
    float4 lp = *(const float4*)(outp + t * Dd);  // 4 partials from K1
    linv[t] = 1.0f / (lp.x + lp.y + lp.z + lp.w);
  }
  __syncthreads();

  int mt = w & 1;
  int par = w >> 1;
  int mrow = mt * 16 + l16;
  float li = linv[mrow];

  f32x4 oacc[4];
#pragma unroll
  for (int dt = 0; dt < 4; ++dt) {
    oacc[dt][0] = 0.f; oacc[dt][1] = 0.f; oacc[dt][2] = 0.f; oacc[dt][3] = 0.f;
  }

  for (int it = 0; it < 16; ++it) {
    int k0 = it << 6;
    __syncthreads();  // prior-iter vt reads done
    {
      int row = t >> 2;          // k index within tile
      int colb = (t & 3) << 4;   // d index
#pragma unroll
      for (int i = 0; i < 4; ++i) {
        float4 v4 = *(const float4*)(Vp + (size_t)(k0 + row) * Dd + colb + i * 4);
        vt[colb + i * 4 + 0][row] = f2bf(v4.x);
        vt[colb + i * 4 + 1][row] = f2bf(v4.y);
        vt[colb + i * 4 + 2][row] = f2bf(v4.z);
        vt[colb + i * 4 + 3][row] = f2bf(v4.w);
      }
    }
    __syncthreads();
    float* sp = attp + (size_t)mrow * Ss + k0 + par * 32 + quad * 8;
    float4 s0 = *(const float4*)sp;
    float4 s1 = *(const float4*)(sp + 4);
    float p0 = s0.x * li, p1 = s0.y * li, p2 = s0.z * li, p3 = s0.w * li;
    float p4 = s1.x * li, p5 = s1.y * li, p6 = s1.z * li, p7 = s1.w * li;
    *(float4*)sp = make_float4(p0, p1, p2, p3);
    *(float4*)(sp + 4) = make_float4(p4, p5, p6, p7);
    bf16x8 af;
    af[0] = (short)f2bf(p0); af[1] = (short)f2bf(p1);
    af[2] = (short)f2bf(p2); af[3] = (short)f2bf(p3);
    af[4] = (short)f2bf(p4); af[5] = (short)f2bf(p5);
    af[6] = (short)f2bf(p6); af[7] = (short)f2bf(p7);
#pragma unroll
    for (int dt = 0; dt < 4; ++dt) {
      bf16x8 bfr = *(const bf16x8*)&vt[dt * 16 + l16][par * 32 + quad * 8];
      oacc[dt] = __builtin_amdgcn_mfma_f32_16x16x32_bf16(af, bfr, oacc[dt], 0, 0, 0);
    }
  }
  // merge k-parities and store output (overwrites the partial-sum scratch)
  __syncthreads();
  if (par == 0) {
#pragma unroll
    for (int dt = 0; dt < 4; ++dt)
#pragma unroll
      for (int r = 0; r < 4; ++r)
        omerge[mt * 16 + quad * 4 + r][dt * 16 + l16] = oacc[dt][r];
  }
  __syncthreads();
  if (par == 1) {
#pragma unroll
    for (int dt = 0; dt < 4; ++dt)
#pragma unroll
      for (int r = 0; r < 4; ++r)
        omerge[mt * 16 + quad * 4 + r][dt * 16 + l16] += oacc[dt][r];
  }
  __syncthreads();
  {
    int row = t >> 3;
    int col = (t & 7) << 3;
    float4 o0 = *(const float4*)&omerge[row][col];
    float4 o1 = *(const float4*)&omerge[row][col + 4];
    *(float4*)(outp + row * Dd + col) = o0;
    *(float4*)(outp + row * Dd + col + 4) = o1;
  }
}

extern "C" void kernel_launch(void* const* d_in, const int* in_sizes, int n_in,
                              void* d_out, int out_size, void* d_ws, size_t ws_size,
                              hipStream_t stream) {
  const float* Q = (const float*)d_in[0];
  const float* K = (const float*)d_in[1];
  const float* V = (const float*)d_in[2];
  const float* dtw = (const float*)d_in[3];
  const int* mask = (const int*)d_in[4];
  const float* W = (const float*)d_in[5];
  const float* bv = (const float*)d_in[6];
  float* out = (float*)d_out;
  float* attn = out + (size_t)Bq * Hh * Ss * Dd;  // attention region of d_out

  score_kernel<<<Bq * 32 * 4, 512, 0, stream>>>(Q, K, dtw, mask, W, bv, attn, out);
  pv_kernel<<<Bq * Hh * (Ss / 32), 256, 0, stream>>>(V, out, attn);
}